// Round 3
// baseline (751.007 us; speedup 1.0000x reference)
//
#include <hip/hip_runtime.h>
#include <hip/hip_bf16.h>

#define NGAUSS   50
#define HID      512
#define EMBD     256
#define XD       768          // HID + EMBD
#define EBLK     64           // edges per block
#define XPAD     776          // x row stride in elements (1552B: 16B-aligned)
#define GPAD     80           // g row stride
#define NT_TOT   32           // 512/16 n-tiles
#define KT_MAIN  24           // 768/32 k-slices
#define XBYTES   (EBLK * XPAD * 2)     // 99328
#define SCRB     12288                 // phase-4 partial buffer (aliases s_g)

typedef __attribute__((ext_vector_type(8))) short   bfrag;   // 8 bf16 (A/B operand)
typedef __attribute__((ext_vector_type(4))) float   facc;    // 4 f32 (C/D)
typedef __attribute__((ext_vector_type(8))) unsigned short u16x8;
typedef __attribute__((ext_vector_type(4))) unsigned short u16x4;

static __device__ __forceinline__ unsigned short f2bf(float f) {
    union { float f; unsigned u; } v; v.f = f;
    unsigned r = v.u + 0x7FFF + ((v.u >> 16) & 1);   // RTNE
    return (unsigned short)(r >> 16);
}

// ---------------- K0: one-time weight conversion into fragment-linear bf16 ----------------
// B-fragment for (kt,nt): element j of lane l = W[k = kt*32 + (l>>4)*8 + j][col = nt*16 + (l&15)]
__global__ __launch_bounds__(256) void prep_weights(
    const float* __restrict__ W1, const float* __restrict__ W_rbf, const float* __restrict__ W2,
    unsigned short* __restrict__ W1f, unsigned short* __restrict__ Wrbff, unsigned short* __restrict__ W2f)
{
    const int gid = blockIdx.x * 256 + threadIdx.x;
    const int N1 = KT_MAIN * NT_TOT * 64;            // 49152
    const int N2 = 2 * NT_TOT * 64;                  // 4096
    const int N3 = 16 * 64;                          // 1024
    if (gid < N1) {
        int lane = gid & 63, tmp = gid >> 6, nt = tmp & 31, kt = tmp >> 5;
        int c = nt * 16 + (lane & 15);
        int kb = kt * 32 + ((lane >> 4) << 3);
        #pragma unroll
        for (int j = 0; j < 8; ++j)
            W1f[gid * 8 + j] = f2bf(W1[(size_t)(kb + j) * HID + c]);
    } else if (gid < N1 + N2) {
        int g2 = gid - N1;
        int lane = g2 & 63, tmp = g2 >> 6, nt = tmp & 31, kt = tmp >> 5;
        int c = nt * 16 + (lane & 15);
        int kb = kt * 32 + ((lane >> 4) << 3);
        #pragma unroll
        for (int j = 0; j < 8; ++j) {
            int k = kb + j;
            Wrbff[g2 * 8 + j] = (k < NGAUSS) ? f2bf(W_rbf[(size_t)k * HID + c]) : (unsigned short)0;
        }
    } else if (gid < N1 + N2 + N3) {
        int g3 = gid - N1 - N2;
        int lane = g3 & 63, kt = g3 >> 6;
        int col = lane & 15;
        int kb = kt * 32 + ((lane >> 4) << 3);
        #pragma unroll
        for (int j = 0; j < 8; ++j)
            W2f[g3 * 8 + j] = (col < 8) ? f2bf(W2[(size_t)(kb + j) * 8 + col]) : (unsigned short)0;
    }
}

// ---------------- main fused kernel: 1024 threads, 16 waves (2 M-groups x 8 N-groups) ----------------
__global__ __launch_bounds__(1024, 4) void pair_embed_mfma(
    const int* __restrict__ anum,
    const int* __restrict__ row_index,
    const int* __restrict__ col_index,
    const float* __restrict__ dist,
    const float* __restrict__ b_rbf,
    const float* __restrict__ emb_table,
    const float* __restrict__ b1,
    const float* __restrict__ b2,
    const unsigned short* __restrict__ W1f,
    const unsigned short* __restrict__ Wrbff,
    const unsigned short* __restrict__ W2f,
    float* __restrict__ out,
    int n)
{
    extern __shared__ char smem[];
    unsigned short* s_x  = (unsigned short*)smem;                 // [64][XPAD] bf16
    unsigned short* s_g  = (unsigned short*)(smem + XBYTES);      // [64][GPAD] bf16 (phases 1-2)
    float*          s_scr = (float*)(smem + XBYTES);              // phase-4 partials (alias)
    float*          s_d  = (float*)(smem + XBYTES + SCRB);
    int*            s_pid = (int*)(smem + XBYTES + SCRB + 256);

    const int t = threadIdx.x, lane = t & 63, w = t >> 6;   // w: 0..15
    const int e0 = blockIdx.x * EBLK;
    const int lq = lane >> 4;          // 0..3
    const int lr = lane & 15;

    // ---- phase 0: metadata ----
    if (t < EBLK) {
        int e = e0 + t; if (e >= n) e = n - 1;
        s_d[t] = dist[e];
        s_pid[t] = anum[row_index[e]] + 100 * anum[col_index[e]];
    }
    __syncthreads();

    // ---- phase 1a: gaussians -> s_g (bf16, K padded to 64) ----
    {
        const float sp = 12.0f / 49.0f;
        const float coeff = -0.5f / (sp * sp);
        int e = t >> 4, j0 = (t & 15) * 4;
        float d = s_d[e];
        u16x4 gv;
        #pragma unroll
        for (int j = 0; j < 4; ++j) {
            int jj = j0 + j;
            float v = d - (float)jj * sp;
            float gq = (jj < NGAUSS) ? __expf(coeff * v * v) : 0.0f;
            gv[j] = f2bf(gq);
        }
        *(u16x4*)&s_g[e * GPAD + j0] = gv;
    }
    // ---- phase 1b: emb gather -> s_x[e][512..767] (bf16) ----
    {
        #pragma unroll
        for (int i = 0; i < 4; ++i) {
            int e = w * 4 + i;
            const float4 v = *(const float4*)&emb_table[(size_t)s_pid[e] * EMBD + lane * 4];
            u16x4 bv; bv[0] = f2bf(v.x); bv[1] = f2bf(v.y); bv[2] = f2bf(v.z); bv[3] = f2bf(v.w);
            *(u16x4*)&s_x[e * XPAD + HID + lane * 4] = bv;
        }
    }
    __syncthreads();

    const int mg  = w >> 3;      // 0..1  (32 rows)
    const int ng  = w & 7;       // 0..7  (64 cols)
    const int ntb = ng * 4;      // first n-tile

    // ---- phase 2: rbf = g @ W_rbf + b_rbf  (MFMA, K=64 padded) ----
    float rbf_reg[2][4][4];
    {
        facc racc[2][4] = {};     // [mt2][ntl]
        #pragma unroll
        for (int kt = 0; kt < 2; ++kt) {
            bfrag a[2];
            #pragma unroll
            for (int mt2 = 0; mt2 < 2; ++mt2)
                a[mt2] = *(const bfrag*)&s_g[((mg * 2 + mt2) * 16 + lr) * GPAD + kt * 32 + lq * 8];
            #pragma unroll
            for (int ntl = 0; ntl < 4; ++ntl) {
                bfrag b = *(const bfrag*)&Wrbff[((size_t)(kt * NT_TOT + ntb + ntl) * 64 + lane) * 8];
                #pragma unroll
                for (int mt2 = 0; mt2 < 2; ++mt2)
                    racc[mt2][ntl] = __builtin_amdgcn_mfma_f32_16x16x32_bf16(a[mt2], b, racc[mt2][ntl], 0, 0, 0);
            }
        }
        #pragma unroll
        for (int ntl = 0; ntl < 4; ++ntl) {
            int col = (ntb + ntl) * 16 + lr;
            float bb = b_rbf[col];
            #pragma unroll
            for (int mt2 = 0; mt2 < 2; ++mt2) {
                #pragma unroll
                for (int r = 0; r < 4; ++r) {
                    float vv = racc[mt2][ntl][r] + bb;
                    rbf_reg[mt2][ntl][r] = vv;
                    s_x[((mg * 2 + mt2) * 16 + lq * 4 + r) * XPAD + col] = f2bf(vv);
                }
            }
        }
    }
    __syncthreads();

    // ---- phase 3: main GEMM  preact = x @ W1 ----
    facc acc[2][4] = {};
    {
        const unsigned short* pB = W1f + ((size_t)ntb * 64 + lane) * 8;
        #pragma unroll 2
        for (int kt = 0; kt < KT_MAIN; ++kt) {
            bfrag a[2];
            #pragma unroll
            for (int mt2 = 0; mt2 < 2; ++mt2)
                a[mt2] = *(const bfrag*)&s_x[((mg * 2 + mt2) * 16 + lr) * XPAD + kt * 32 + lq * 8];
            #pragma unroll
            for (int ntl = 0; ntl < 4; ++ntl) {
                bfrag b = *(const bfrag*)&pB[(size_t)kt * NT_TOT * 64 * 8 + ntl * 64 * 8];
                #pragma unroll
                for (int mt2 = 0; mt2 < 2; ++mt2)
                    acc[mt2][ntl] = __builtin_amdgcn_mfma_f32_16x16x32_bf16(a[mt2], b, acc[mt2][ntl], 0, 0, 0);
            }
        }
    }
    __syncthreads();   // everyone done reading x

    // ---- epilogue: h = silu(preact + b1) * rbf ; write h (bf16) over s_x[:, 0..511] ----
    #pragma unroll
    for (int ntl = 0; ntl < 4; ++ntl) {
        int col = (ntb + ntl) * 16 + lr;
        float bb = b1[col];
        #pragma unroll
        for (int mt2 = 0; mt2 < 2; ++mt2) {
            #pragma unroll
            for (int r = 0; r < 4; ++r) {
                float v = acc[mt2][ntl][r] + bb;
                float sg = __builtin_amdgcn_rcpf(1.0f + __expf(-v));
                float h = v * sg * rbf_reg[mt2][ntl][r];
                s_x[((mg * 2 + mt2) * 16 + lq * 4 + r) * XPAD + col] = f2bf(h);
            }
        }
    }
    __syncthreads();

    // ---- phase 4: att = h @ W2 (+b2), N padded to 16; 4-way K-split across waves ----
    {
        const int mt4 = w & 3;          // m-tile (16 rows)
        const int ks  = w >> 2;         // k-quarter 0..3 (4 kt each; K=512 -> 16 kt)
        facc a4 = {};
        #pragma unroll
        for (int kq = 0; kq < 4; ++kq) {
            int kt = ks * 4 + kq;
            bfrag av = *(const bfrag*)&s_x[(mt4 * 16 + lr) * XPAD + kt * 32 + lq * 8];
            bfrag bv = *(const bfrag*)&W2f[((size_t)kt * 64 + lane) * 8];
            a4 = __builtin_amdgcn_mfma_f32_16x16x32_bf16(av, bv, a4, 0, 0, 0);
        }
        if (ks > 0) *(facc*)&s_scr[(((ks - 1) * 4 + mt4) * 64 + lane) * 4] = a4;
        __syncthreads();
        if (ks == 0) {
            #pragma unroll
            for (int p = 0; p < 3; ++p) {
                facc oth = *(const facc*)&s_scr[((size_t)(p * 4 + mt4) * 64 + lane) * 4];
                #pragma unroll
                for (int r = 0; r < 4; ++r) a4[r] += oth[r];
            }
            if (lr < 8) {
                float bb = b2[lr];
                #pragma unroll
                for (int r = 0; r < 4; ++r) {
                    int e = e0 + mt4 * 16 + lq * 4 + r;
                    if (e < n) out[(size_t)lr * n + e] = a4[r] + bb;
                }
            }
        }
    }
}

extern "C" void kernel_launch(void* const* d_in, const int* in_sizes, int n_in,
                              void* d_out, int out_size, void* d_ws, size_t ws_size,
                              hipStream_t stream) {
    const int*   anum      = (const int*)d_in[0];
    const int*   row_index = (const int*)d_in[1];
    const int*   col_index = (const int*)d_in[2];
    const float* dist      = (const float*)d_in[3];
    const float* W_rbf     = (const float*)d_in[4];
    const float* b_rbf     = (const float*)d_in[5];
    const float* emb_table = (const float*)d_in[6];
    const float* W1        = (const float*)d_in[7];
    const float* b1        = (const float*)d_in[8];
    const float* W2        = (const float*)d_in[9];
    const float* b2        = (const float*)d_in[10];
    float* out = (float*)d_out;

    unsigned short* W1f   = (unsigned short*)d_ws;                    // 24*32*64*8 ushorts
    unsigned short* Wrbff = W1f + (size_t)KT_MAIN * NT_TOT * 64 * 8;
    unsigned short* W2f   = Wrbff + (size_t)2 * NT_TOT * 64 * 8;

    const int n_edges = in_sizes[3];

    prep_weights<<<213, 256, 0, stream>>>(W1, W_rbf, W2, W1f, Wrbff, W2f);

    const int grid = (n_edges + EBLK - 1) / EBLK;
    const size_t lds_bytes = XBYTES + SCRB + 256 + 256;
    pair_embed_mfma<<<grid, 1024, lds_bytes, stream>>>(
        anum, row_index, col_index, dist, b_rbf, emb_table, b1, b2,
        W1f, Wrbff, W2f, out, n_edges);
}

// Round 4
// 229.177 us; speedup vs baseline: 3.2770x; 3.2770x over previous
//
#include <hip/hip_runtime.h>
#include <hip/hip_bf16.h>

#define NGAUSS   50
#define HID      512
#define EMBD     256
#define NPID     10000         // 100*100 pair types
#define EBLK     64            // edges per block
#define GPAD     72            // u16 stride for g rows (144B)
#define PPAD     520           // u16 stride for P/h rows (1040B)
#define EPAD     264           // u16 stride for emb stage rows in P-GEMM (528B)

typedef __attribute__((ext_vector_type(8))) short   bfrag;   // 8 bf16
typedef __attribute__((ext_vector_type(4))) float   facc;    // 4 f32
typedef __attribute__((ext_vector_type(8))) unsigned short u16x8;
typedef __attribute__((ext_vector_type(4))) unsigned short u16x4;

// ---- workspace layout (bytes) ----
#define PBF_OFF    0                         // u16 [10000*512]      10,240,000
#define WC32_OFF   10240000                  // f32 [50*512]            102,400
#define BIAS1_OFF  10342400                  // f32 [512]                 2,048
#define W1BF_OFF   10344448                  // u16 [8*32*64*8]         262,144
#define WRBF_OFF   10606592                  // u16 [2*32*64*8]          65,536
#define WCBF_OFF   10672128                  // u16 [2*32*64*8]          65,536
#define W2F_OFF    10737664                  // u16 [16*64*8]            16,384

static __device__ __forceinline__ unsigned short f2bf(float f) {
    union { float f; unsigned u; } v; v.f = f;
    unsigned r = v.u + 0x7FFF + ((v.u >> 16) & 1);   // RTNE
    return (unsigned short)(r >> 16);
}
static __device__ __forceinline__ float bf2f(unsigned short u) {
    union { unsigned u; float f; } v; v.u = ((unsigned)u) << 16;
    return v.f;
}

// ================= K0: Wcomb = W_rbf@W1top (fp32), bias1 = b_rbf@W1top + b1, pack W1bot/Wrbf/W2 frags =================
// Fragment (kt,nt): elem j of lane l = W[k = kt*32 + (l>>4)*8 + j][col = nt*16 + (l&15)]
__global__ __launch_bounds__(256) void prep0(
    const float* __restrict__ W_rbf, const float* __restrict__ b_rbf,
    const float* __restrict__ W1, const float* __restrict__ b1,
    const float* __restrict__ W2, char* __restrict__ ws)
{
    const int b = blockIdx.x, tid = threadIdx.x;
    if (b < 102) {
        // ---- Wcomb fp32 (rows 0..49) and bias1 (row 50) ----
        const int j = b >> 1, chalf = b & 1;
        const int c = chalf * 256 + tid;
        const float* row = (j < NGAUSS) ? &W_rbf[(size_t)j * HID] : b_rbf;
        float a0 = 0.f, a1 = 0.f, a2 = 0.f, a3 = 0.f;
        for (int k = 0; k < HID; k += 4) {
            a0 += row[k + 0] * W1[(size_t)(k + 0) * HID + c];
            a1 += row[k + 1] * W1[(size_t)(k + 1) * HID + c];
            a2 += row[k + 2] * W1[(size_t)(k + 2) * HID + c];
            a3 += row[k + 3] * W1[(size_t)(k + 3) * HID + c];
        }
        float acc = (a0 + a1) + (a2 + a3);
        if (j < NGAUSS) ((float*)(ws + WC32_OFF))[j * HID + c] = acc;
        else            ((float*)(ws + BIAS1_OFF))[c] = acc + b1[c];
    } else if (b < 166) {
        // ---- pack W1bot fragments: kt 0..7 over K=512..767 ----
        const int gid = (b - 102) * 256 + tid;          // [0, 16384)
        const int lane = gid & 63, tmp = gid >> 6, nt = tmp & 31, kt = tmp >> 5;
        const int c  = nt * 16 + (lane & 15);
        const int kb = HID + kt * 32 + ((lane >> 4) << 3);
        unsigned short* dst = (unsigned short*)(ws + W1BF_OFF);
        #pragma unroll
        for (int j = 0; j < 8; ++j)
            dst[(size_t)gid * 8 + j] = f2bf(W1[(size_t)(kb + j) * HID + c]);
    } else if (b < 182) {
        // ---- pack W_rbf fragments: kt 0..1 (K padded to 64) ----
        const int gid = (b - 166) * 256 + tid;          // [0, 4096)
        const int lane = gid & 63, tmp = gid >> 6, nt = tmp & 31, kt = tmp >> 5;
        const int c  = nt * 16 + (lane & 15);
        const int kb = kt * 32 + ((lane >> 4) << 3);
        unsigned short* dst = (unsigned short*)(ws + WRBF_OFF);
        #pragma unroll
        for (int j = 0; j < 8; ++j) {
            int k = kb + j;
            dst[(size_t)gid * 8 + j] = (k < NGAUSS) ? f2bf(W_rbf[(size_t)k * HID + c]) : (unsigned short)0;
        }
    } else {
        // ---- pack W2 fragments: kt 0..15, N padded to 16 ----
        const int gid = (b - 182) * 256 + tid;          // [0, 1024)
        const int lane = gid & 63, kt = gid >> 6;
        const int col = lane & 15;
        const int kb  = kt * 32 + ((lane >> 4) << 3);
        unsigned short* dst = (unsigned short*)(ws + W2F_OFF);
        #pragma unroll
        for (int j = 0; j < 8; ++j)
            dst[(size_t)gid * 8 + j] = (col < 8) ? f2bf(W2[(size_t)(kb + j) * 8 + col]) : (unsigned short)0;
    }
}

// ================= K1: pack Wcomb frags + P = emb_table @ W1bot  (bf16 MFMA, fp32 accum) =================
__global__ __launch_bounds__(512) void prep1(
    const float* __restrict__ emb_table, char* __restrict__ ws)
{
    const int b = blockIdx.x, t = threadIdx.x;
    if (b < 8) {
        // ---- pack Wcomb fragments (kt 0..1, rows >= 50 zero) ----
        const int gid = b * 512 + t;                    // [0, 4096)
        const int lane = gid & 63, tmp = gid >> 6, nt = tmp & 31, kt = tmp >> 5;
        const int c  = nt * 16 + (lane & 15);
        const int kb = kt * 32 + ((lane >> 4) << 3);
        const float* wc = (const float*)(ws + WC32_OFF);
        unsigned short* dst = (unsigned short*)(ws + WCBF_OFF);
        #pragma unroll
        for (int j = 0; j < 8; ++j) {
            int k = kb + j;
            dst[(size_t)gid * 8 + j] = (k < NGAUSS) ? f2bf(wc[k * HID + c]) : (unsigned short)0;
        }
        return;
    }
    // ---- P GEMM: 64 rows of emb_table @ W1bot ----
    __shared__ unsigned short s_e[64 * EPAD];
    const int pb = b - 8;                               // 0..156
    const int lane = t & 63, w = t >> 6;
    const int lq = lane >> 4, lr = lane & 15;
    {
        int row = t >> 3;
        int grow = pb * 64 + row; if (grow >= NPID) grow = NPID - 1;
        int c0 = (t & 7) * 32;
        #pragma unroll
        for (int ii = 0; ii < 8; ++ii) {
            const float4 v = *(const float4*)&emb_table[(size_t)grow * EMBD + c0 + ii * 4];
            u16x4 bv; bv[0] = f2bf(v.x); bv[1] = f2bf(v.y); bv[2] = f2bf(v.z); bv[3] = f2bf(v.w);
            *(u16x4*)&s_e[row * EPAD + c0 + ii * 4] = bv;
        }
    }
    __syncthreads();
    const int ntb = w * 4;
    const unsigned short* W1bf = (const unsigned short*)(ws + W1BF_OFF);
    unsigned short* Pbf = (unsigned short*)(ws + PBF_OFF);
    facc acc[4][4] = {};
    for (int kt = 0; kt < 8; ++kt) {
        bfrag a[4];
        #pragma unroll
        for (int mt = 0; mt < 4; ++mt)
            a[mt] = *(const bfrag*)&s_e[(mt * 16 + lr) * EPAD + kt * 32 + lq * 8];
        #pragma unroll
        for (int ntl = 0; ntl < 4; ++ntl) {
            bfrag bv = *(const bfrag*)&W1bf[((size_t)(kt * 32 + ntb + ntl) * 64 + lane) * 8];
            #pragma unroll
            for (int mt = 0; mt < 4; ++mt)
                acc[mt][ntl] = __builtin_amdgcn_mfma_f32_16x16x32_bf16(a[mt], bv, acc[mt][ntl], 0, 0, 0);
        }
    }
    #pragma unroll
    for (int ntl = 0; ntl < 4; ++ntl) {
        int col = (ntb + ntl) * 16 + lr;
        #pragma unroll
        for (int mt = 0; mt < 4; ++mt) {
            #pragma unroll
            for (int r = 0; r < 4; ++r) {
                int grow = pb * 64 + mt * 16 + lq * 4 + r;
                if (grow < NPID) Pbf[(size_t)grow * HID + col] = f2bf(acc[mt][ntl][r]);
            }
        }
    }
}

// ================= main fused kernel: 512 threads, 8 waves =================
__global__ __launch_bounds__(512, 4) void pair_embed_mfma(
    const int* __restrict__ anum,
    const int* __restrict__ row_index,
    const int* __restrict__ col_index,
    const float* __restrict__ dist,
    const float* __restrict__ b_rbf,
    const float* __restrict__ b2,
    const char* __restrict__ ws,
    float* __restrict__ out,
    int n)
{
    extern __shared__ char smem[];
    unsigned short* s_buf = (unsigned short*)smem;                    // [64][PPAD]: P rows -> h rows (in place)
    unsigned short* s_g   = (unsigned short*)(smem + 64 * PPAD * 2);  // [64][GPAD]
    float*          s_scr = (float*)(smem + 64 * PPAD * 2 + 64 * GPAD * 2);   // phase-4 partials 4KB
    float*          s_d   = (float*)(smem + 64 * PPAD * 2 + 64 * GPAD * 2 + 4096);
    int*            s_pid = (int*)(smem + 64 * PPAD * 2 + 64 * GPAD * 2 + 4096 + 256);

    const unsigned short* Pbf   = (const unsigned short*)(ws + PBF_OFF);
    const float*          bias1 = (const float*)(ws + BIAS1_OFF);
    const unsigned short* Wrbff = (const unsigned short*)(ws + WRBF_OFF);
    const unsigned short* Wcbf  = (const unsigned short*)(ws + WCBF_OFF);
    const unsigned short* W2f   = (const unsigned short*)(ws + W2F_OFF);

    const int t = threadIdx.x, lane = t & 63, w = t >> 6;
    const int e0 = blockIdx.x * EBLK;
    const int lq = lane >> 4, lr = lane & 15;

    // ---- phase 0: metadata ----
    if (t < EBLK) {
        int e = e0 + t; if (e >= n) e = n - 1;
        s_d[t] = dist[e];
        s_pid[t] = anum[row_index[e]] + 100 * anum[col_index[e]];
    }
    __syncthreads();

    // ---- phase 1a: gaussians -> s_g (K padded to 64) ----
    {
        const float sp = 12.0f / 49.0f;
        const float coeff = -0.5f / (sp * sp);
        int e = t >> 3, j0 = (t & 7) * 8;
        float d = s_d[e];
        u16x8 gv;
        #pragma unroll
        for (int j = 0; j < 8; ++j) {
            int jj = j0 + j;
            float v = d - (float)jj * sp;
            float gq = (jj < NGAUSS) ? __expf(coeff * v * v) : 0.0f;
            gv[j] = f2bf(gq);
        }
        *(u16x8*)&s_g[e * GPAD + j0] = gv;
    }
    // ---- phase 1b: gather P[pid] rows -> s_buf ----
    {
        #pragma unroll
        for (int i = 0; i < 8; ++i) {
            int row = w * 8 + i;
            const u16x8 v = *(const u16x8*)&Pbf[(size_t)s_pid[row] * HID + lane * 8];
            *(u16x8*)&s_buf[row * PPAD + lane * 8] = v;
        }
    }
    __syncthreads();

    const int ntb = w * 4;   // this wave's 4 n-tiles (64 cols)

    // ---- phase 2+3: twin K=64 GEMMs (rbf & preact) + fused epilogue per ntl ----
    bfrag a[4][2];
    #pragma unroll
    for (int mt = 0; mt < 4; ++mt)
        #pragma unroll
        for (int kt = 0; kt < 2; ++kt)
            a[mt][kt] = *(const bfrag*)&s_g[(mt * 16 + lr) * GPAD + kt * 32 + lq * 8];

    #pragma unroll
    for (int ntl = 0; ntl < 4; ++ntl) {
        const int nt = ntb + ntl;
        bfrag bR0 = *(const bfrag*)&Wrbff[((size_t)(0 * 32 + nt) * 64 + lane) * 8];
        bfrag bR1 = *(const bfrag*)&Wrbff[((size_t)(1 * 32 + nt) * 64 + lane) * 8];
        bfrag bC0 = *(const bfrag*)&Wcbf [((size_t)(0 * 32 + nt) * 64 + lane) * 8];
        bfrag bC1 = *(const bfrag*)&Wcbf [((size_t)(1 * 32 + nt) * 64 + lane) * 8];
        facc racc[4] = {}, cacc[4] = {};
        #pragma unroll
        for (int mt = 0; mt < 4; ++mt) {
            racc[mt] = __builtin_amdgcn_mfma_f32_16x16x32_bf16(a[mt][0], bR0, racc[mt], 0, 0, 0);
            cacc[mt] = __builtin_amdgcn_mfma_f32_16x16x32_bf16(a[mt][0], bC0, cacc[mt], 0, 0, 0);
        }
        #pragma unroll
        for (int mt = 0; mt < 4; ++mt) {
            racc[mt] = __builtin_amdgcn_mfma_f32_16x16x32_bf16(a[mt][1], bR1, racc[mt], 0, 0, 0);
            cacc[mt] = __builtin_amdgcn_mfma_f32_16x16x32_bf16(a[mt][1], bC1, cacc[mt], 0, 0, 0);
        }
        // epilogue: preact = cacc + bias1 + P ; h = silu(preact) * (racc + b_rbf) ; in-place h over P
        const int col = nt * 16 + lr;
        const float brb = b_rbf[col];
        const float bs1 = bias1[col];
        #pragma unroll
        for (int mt = 0; mt < 4; ++mt) {
            #pragma unroll
            for (int r = 0; r < 4; ++r) {
                const int row = mt * 16 + lq * 4 + r;
                const float rbf = racc[mt][r] + brb;
                const float pv  = bf2f(s_buf[row * PPAD + col]);
                const float pre = cacc[mt][r] + bs1 + pv;
                const float h   = pre * __builtin_amdgcn_rcpf(1.0f + __expf(-pre)) * rbf;
                s_buf[row * PPAD + col] = f2bf(h);
            }
        }
    }
    __syncthreads();

    // ---- phase 4: att = h @ W2 (+b2), N padded to 16; 2-way K-split across waves ----
    {
        const int mt4 = w & 3;          // m-tile (16 rows)
        const int ks  = w >> 2;         // k-half 0..1 (8 kt each; K=512 -> 16 kt)
        facc a4 = {};
        #pragma unroll
        for (int kq = 0; kq < 8; ++kq) {
            int kt = ks * 8 + kq;
            bfrag av = *(const bfrag*)&s_buf[(mt4 * 16 + lr) * PPAD + kt * 32 + lq * 8];
            bfrag bv = *(const bfrag*)&W2f[((size_t)kt * 64 + lane) * 8];
            a4 = __builtin_amdgcn_mfma_f32_16x16x32_bf16(av, bv, a4, 0, 0, 0);
        }
        if (ks == 1) *(facc*)&s_scr[(mt4 * 64 + lane) * 4] = a4;
        __syncthreads();
        if (ks == 0) {
            facc oth = *(const facc*)&s_scr[(mt4 * 64 + lane) * 4];
            if (lr < 8) {
                float bb = b2[lr];
                #pragma unroll
                for (int r = 0; r < 4; ++r) {
                    int e = e0 + mt4 * 16 + lq * 4 + r;
                    if (e < n) out[(size_t)lr * n + e] = a4[r] + oth[r] + bb;
                }
            }
        }
    }
}

extern "C" void kernel_launch(void* const* d_in, const int* in_sizes, int n_in,
                              void* d_out, int out_size, void* d_ws, size_t ws_size,
                              hipStream_t stream) {
    const int*   anum      = (const int*)d_in[0];
    const int*   row_index = (const int*)d_in[1];
    const int*   col_index = (const int*)d_in[2];
    const float* dist      = (const float*)d_in[3];
    const float* W_rbf     = (const float*)d_in[4];
    const float* b_rbf     = (const float*)d_in[5];
    const float* emb_table = (const float*)d_in[6];
    const float* W1        = (const float*)d_in[7];
    const float* b1        = (const float*)d_in[8];
    const float* W2        = (const float*)d_in[9];
    const float* b2        = (const float*)d_in[10];
    float* out = (float*)d_out;
    char* ws = (char*)d_ws;

    const int n_edges = in_sizes[3];

    prep0<<<186, 256, 0, stream>>>(W_rbf, b_rbf, W1, b1, W2, ws);
    prep1<<<8 + 157, 512, 0, stream>>>(emb_table, ws);

    const int grid = (n_edges + EBLK - 1) / EBLK;
    const size_t lds_bytes = 64 * PPAD * 2 + 64 * GPAD * 2 + 4096 + 256 + 256;  // 80384
    pair_embed_mfma<<<grid, 512, lds_bytes, stream>>>(
        anum, row_index, col_index, dist, b_rbf, b2, ws, out, n_edges);
}